// Round 6
// baseline (612.451 us; speedup 1.0000x reference)
//
#include <hip/hip_runtime.h>
#include <cmath>

#define BB 8
#define CC 256
#define CQ 64
#define NN 4096
constexpr float INV_N = 1.0f / 4096.0f;

typedef __attribute__((ext_vector_type(8))) short short8;
typedef __attribute__((ext_vector_type(4))) short short4v;
typedef __attribute__((ext_vector_type(4))) float float4v;

__device__ __forceinline__ short f2bf(float f) {
  union { float f; unsigned u; } x; x.f = f;
  unsigned r = x.u + 0x7fffu + ((x.u >> 16) & 1u);
  return (short)(r >> 16);
}

// ---------------------------------------------------------------------------
// prep: blocks 0..63 -> Wv' = Wg@Wv (fp32 accum, bf16 out), 32x32 tiles;
//       block 64 -> convert wq,wk to bf16; block 65 -> bv' = Wg@bv (fp32).
// ---------------------------------------------------------------------------
__global__ __launch_bounds__(256) void prep_kernel(
    const float* __restrict__ wq, const float* __restrict__ wk,
    const float* __restrict__ wv, const float* __restrict__ wg,
    const float* __restrict__ bv,
    short* __restrict__ wqbf, short* __restrict__ wkbf,
    short* __restrict__ wvpbf, float* __restrict__ bvp) {
  const int bx = blockIdx.x;
  const int tid = threadIdx.x;
  if (bx < 64) {
    const int o0 = (bx >> 3) * 32, c0 = (bx & 7) * 32;
    const int cc = tid & 31, oo = tid >> 5;  // oo 0..7
    float acc[4] = {0.f, 0.f, 0.f, 0.f};
    for (int u = 0; u < 256; ++u) {
      const float xv = wv[(size_t)u * 256 + c0 + cc];
#pragma unroll
      for (int i = 0; i < 4; ++i)
        acc[i] += wg[(size_t)(o0 + oo * 4 + i) * 256 + u] * xv;
    }
#pragma unroll
    for (int i = 0; i < 4; ++i)
      wvpbf[(size_t)(o0 + oo * 4 + i) * 256 + c0 + cc] = f2bf(acc[i]);
  } else if (bx == 64) {
#pragma unroll 4
    for (int t = 0; t < 16; ++t) {
      const int idx = (t * 256 + tid) * 4;
      const float4 a = *reinterpret_cast<const float4*>(&wq[idx]);
      short4v p; p.x = f2bf(a.x); p.y = f2bf(a.y); p.z = f2bf(a.z); p.w = f2bf(a.w);
      *reinterpret_cast<short4v*>(&wqbf[idx]) = p;
      const float4 b4 = *reinterpret_cast<const float4*>(&wk[idx]);
      short4v q4; q4.x = f2bf(b4.x); q4.y = f2bf(b4.y); q4.z = f2bf(b4.z); q4.w = f2bf(b4.w);
      *reinterpret_cast<short4v*>(&wkbf[idx]) = q4;
    }
  } else {
    float acc = 0.f;
    for (int u = 0; u < 256; ++u) acc += wg[(size_t)tid * 256 + u] * bv[u];
    bvp[tid] = acc;
  }
}

// ---------------------------------------------------------------------------
// qkv: n-tile 32, grid (B, NN/32). Swizzled bf16 x-transpose in LDS; 6
// chunks of 64 output channels (q | k | vtilde0..3) via MFMA. W A-frags:
// first half prefetched before the x-barrier / previous chunk, second half
// covered by first-half MFMAs. waves_per_eu pinned to stop VGPR squeeze.
// ---------------------------------------------------------------------------
__global__ __launch_bounds__(256)
__attribute__((amdgpu_waves_per_eu(4, 4))) void qkv_kernel(
    const float* __restrict__ X,
    const short* __restrict__ wqbf, const short* __restrict__ wkbf,
    const short* __restrict__ wvpbf,
    const float* __restrict__ bq, const float* __restrict__ bk,
    const float* __restrict__ bvp,
    short* __restrict__ qt, short* __restrict__ kt, short* __restrict__ vt) {
  __shared__ short smem[8448 + 2560];
  short* xt = smem;              // [32 n][264 c] bf16, XOR-swizzled chunks
  short* Os = smem + 8448;       // [64 o][40 n] vtilde staging

  const int tid = threadIdx.x;
  const int wid = tid >> 6;
  const int lane = tid & 63, quad = lane >> 4, l16 = lane & 15;
  const int b = blockIdx.x, n0 = blockIdx.y * 32;

  const short* Wsrc[6] = {wqbf, wkbf, wvpbf, wvpbf + 64 * 256,
                          wvpbf + 128 * 256, wvpbf + 192 * 256};
  const int arow = wid * 16 + l16;

  // prefetch chunk 0, first K-half of W (covered by x staging)
  short8 curA[4];
#pragma unroll
  for (int kk = 0; kk < 4; ++kk)
    curA[kk] = *reinterpret_cast<const short8*>(
        &Wsrc[0][(size_t)arow * 256 + kk * 32 + quad * 8]);

  // ---- stage x -> xt[n][c] bf16, packed b64 writes ----
#pragma unroll
  for (int p = 0; p < 2; ++p) {
    const int idx = p * 256 + tid;
    const int cg = idx >> 3;          // 4-channel group 0..63
    const int ng = idx & 7;           // 4-row group 0..7
    float4 xr[4];
#pragma unroll
    for (int j = 0; j < 4; ++j)
      xr[j] = *reinterpret_cast<const float4*>(
          &X[((size_t)b * CC + cg * 4 + j) * NN + n0 + ng * 4]);
    const int colbase = (((cg >> 1) ^ ng) * 8 + (cg & 1) * 4);
#pragma unroll
    for (int r = 0; r < 4; ++r) {
      short4v pk;
      pk.x = f2bf((&xr[0].x)[r]); pk.y = f2bf((&xr[1].x)[r]);
      pk.z = f2bf((&xr[2].x)[r]); pk.w = f2bf((&xr[3].x)[r]);
      *reinterpret_cast<short4v*>(&xt[(ng * 4 + r) * 264 + colbase]) = pk;
    }
  }
  __syncthreads();

#pragma unroll
  for (int ch = 0; ch < 6; ++ch) {
    // second K-half of this chunk's W (covered by first-half MFMAs)
    short8 hiA[4];
#pragma unroll
    for (int kk = 0; kk < 4; ++kk)
      hiA[kk] = *reinterpret_cast<const short8*>(
          &Wsrc[ch][(size_t)arow * 256 + (kk + 4) * 32 + quad * 8]);

    float4v acc2[2];
    acc2[0] = float4v{0.f, 0.f, 0.f, 0.f};
    acc2[1] = float4v{0.f, 0.f, 0.f, 0.f};

#pragma unroll
    for (int kk = 0; kk < 4; ++kk) {
#pragma unroll
      for (int tm = 0; tm < 2; ++tm) {
        const int row = tm * 16 + l16;
        const int swr = (row >> 2) & 7;
        const short8 bfrag = *reinterpret_cast<const short8*>(
            &xt[row * 264 + ((kk * 4 + quad) ^ swr) * 8]);
        acc2[tm] = __builtin_amdgcn_mfma_f32_16x16x32_bf16(curA[kk], bfrag,
                                                           acc2[tm], 0, 0, 0);
      }
    }
    // prefetch next chunk's first K-half
    if (ch < 5) {
#pragma unroll
      for (int kk = 0; kk < 4; ++kk)
        curA[kk] = *reinterpret_cast<const short8*>(
            &Wsrc[ch + 1][(size_t)arow * 256 + kk * 32 + quad * 8]);
    }
#pragma unroll
    for (int kk = 4; kk < 8; ++kk) {
#pragma unroll
      for (int tm = 0; tm < 2; ++tm) {
        const int row = tm * 16 + l16;
        const int swr = (row >> 2) & 7;
        const short8 bfrag = *reinterpret_cast<const short8*>(
            &xt[row * 264 + ((kk * 4 + quad) ^ swr) * 8]);
        acc2[tm] = __builtin_amdgcn_mfma_f32_16x16x32_bf16(hiA[kk - 4], bfrag,
                                                           acc2[tm], 0, 0, 0);
      }
    }

    if (ch < 2) {
      const float* bias = (ch == 0) ? bq : bk;
      const float4v bv4 = *reinterpret_cast<const float4v*>(
          &bias[wid * 16 + quad * 4]);
      short* dst = (ch == 0) ? qt : kt;
#pragma unroll
      for (int tm = 0; tm < 2; ++tm) {
        short4v pk;
#pragma unroll
        for (int r = 0; r < 4; ++r) pk[r] = f2bf(acc2[tm][r] + bv4[r]);
        *reinterpret_cast<short4v*>(
            &dst[((size_t)b * NN + n0 + tm * 16 + l16) * 64 + wid * 16 +
                 quad * 4]) = pk;
      }
    } else {
      const float4v bv4 = *reinterpret_cast<const float4v*>(
          &bvp[(ch - 2) * 64 + wid * 16 + quad * 4]);
      __syncthreads();  // prior chunk's Os reads done
#pragma unroll
      for (int tm = 0; tm < 2; ++tm)
#pragma unroll
        for (int r = 0; r < 4; ++r)
          Os[(wid * 16 + quad * 4 + r) * 40 + tm * 16 + l16] =
              f2bf(acc2[tm][r] + bv4[r]);
      __syncthreads();
      const int o = tid >> 2, ng = (tid & 3) * 8;
      const short8 s0 = *reinterpret_cast<const short8*>(&Os[o * 40 + ng]);
      *reinterpret_cast<short8*>(
          &vt[((size_t)b * CC + (ch - 2) * 64 + o) * NN + n0 + ng]) = s0;
    }
  }
}

// ---------------------------------------------------------------------------
// attn r6: block = 64 m x 256 c, grid (NN/64, B) = 512 = 2 blocks/CU.
// S: wave computes n-slice [wid*16,+16) x all 64 m (as before).
// PV: wave owns ONLY m-tile wid x all 16 c-tiles -> Es reads drop 4x
//     (2 b128/iter instead of 8): kernel moves from LDS-bound to MFMA-bound.
// No S duplication. k frags resident; q prefetched; v from L1/L2 (all 4
// waves read the same 16KB v-chunk). One barrier/iter, Es double-buffered.
// waves_per_eu(2,2): ~190 VGPR live, stop the allocator's 64-reg squeeze.
// ---------------------------------------------------------------------------
__global__ __launch_bounds__(256)
__attribute__((amdgpu_waves_per_eu(2, 2))) void attn_kernel(
    const short* __restrict__ qt, const short* __restrict__ kt,
    const short* __restrict__ vt, const float* __restrict__ bg,
    float* __restrict__ out) {
  __shared__ short Es[2][64 * 72];   // [m][n], 18.4 KB

  const int tid = threadIdx.x;
  const int wid = tid >> 6;
  const int lane = tid & 63, quad = lane >> 4, l16 = lane & 15;
  const int m0 = blockIdx.x * 64;
  const int b = blockIdx.y;

  // k fragments: resident, 4 m-tiles x K64
  short8 kf[4][2];
#pragma unroll
  for (int tm = 0; tm < 4; ++tm)
#pragma unroll
    for (int kk = 0; kk < 2; ++kk)
      kf[tm][kk] = *reinterpret_cast<const short8*>(
          &kt[((size_t)b * NN + m0 + tm * 16 + l16) * 64 + kk * 32 + quad * 8]);

  const short* qrow = &qt[((size_t)b * NN + wid * 16 + l16) * 64 + quad * 8];
  const short* vbase = &vt[((size_t)b * CC + l16) * NN + quad * 8];

  float4v acc[16];
#pragma unroll
  for (int i = 0; i < 16; ++i) acc[i] = float4v{0.f, 0.f, 0.f, 0.f};

  // ---- prologue: S(0) -> Es[0]; prefetch q(1) ----
  short8 aq0 = *reinterpret_cast<const short8*>(qrow);
  short8 aq1 = *reinterpret_cast<const short8*>(qrow + 32);
  {
    float4v s[4];
#pragma unroll
    for (int tm = 0; tm < 4; ++tm) {
      float4v t = {0.f, 0.f, 0.f, 0.f};
      t = __builtin_amdgcn_mfma_f32_16x16x32_bf16(aq0, kf[tm][0], t, 0, 0, 0);
      t = __builtin_amdgcn_mfma_f32_16x16x32_bf16(aq1, kf[tm][1], t, 0, 0, 0);
      s[tm] = t;
    }
#pragma unroll
    for (int tm = 0; tm < 4; ++tm) {
      short4v pk;
#pragma unroll
      for (int r = 0; r < 4; ++r) {
        float sv = s[tm][r];
        sv = (sv > 0.f) ? sv : (__expf(sv) - 1.f);
        pk[r] = f2bf(sv * INV_N);
      }
      *reinterpret_cast<short4v*>(
          &Es[0][(tm * 16 + l16) * 72 + wid * 16 + quad * 4]) = pk;
    }
  }
  aq0 = *reinterpret_cast<const short8*>(qrow + 64 * 64);
  aq1 = *reinterpret_cast<const short8*>(qrow + 64 * 64 + 32);
  __syncthreads();

  for (int it = 0; it < 64; ++it) {
    const int rb = it & 1, wb = rb ^ 1;

    // ---- S(it+1); garbage at it=63 (never read; q over-read lands in kt) --
    float4v s[4];
#pragma unroll
    for (int tm = 0; tm < 4; ++tm) {
      float4v t = {0.f, 0.f, 0.f, 0.f};
      t = __builtin_amdgcn_mfma_f32_16x16x32_bf16(aq0, kf[tm][0], t, 0, 0, 0);
      t = __builtin_amdgcn_mfma_f32_16x16x32_bf16(aq1, kf[tm][1], t, 0, 0, 0);
      s[tm] = t;
    }
#pragma unroll
    for (int tm = 0; tm < 4; ++tm) {
      short4v pk;
#pragma unroll
      for (int r = 0; r < 4; ++r) {
        float sv = s[tm][r];
        sv = (sv > 0.f) ? sv : (__expf(sv) - 1.f);
        pk[r] = f2bf(sv * INV_N);
      }
      *reinterpret_cast<short4v*>(
          &Es[wb][(tm * 16 + l16) * 72 + wid * 16 + quad * 4]) = pk;
    }

    // ---- PV(it): wave's own m-tile only -> 2 b128 Es reads ----
    const short8 be0 = *reinterpret_cast<const short8*>(
        &Es[rb][(wid * 16 + l16) * 72 + quad * 8]);
    const short8 be1 = *reinterpret_cast<const short8*>(
        &Es[rb][(wid * 16 + l16) * 72 + 32 + quad * 8]);
    const short* vn = vbase + (size_t)it * 64;
#pragma unroll
    for (int tc = 0; tc < 16; ++tc) {
      const short8 av0 =
          *reinterpret_cast<const short8*>(vn + (size_t)tc * 16 * NN);
      const short8 av1 =
          *reinterpret_cast<const short8*>(vn + (size_t)tc * 16 * NN + 32);
      acc[tc] = __builtin_amdgcn_mfma_f32_16x16x32_bf16(av0, be0, acc[tc], 0, 0, 0);
      acc[tc] = __builtin_amdgcn_mfma_f32_16x16x32_bf16(av1, be1, acc[tc], 0, 0, 0);
    }

    // prefetch q(it+2) (over-read at it>=62 lands in kt — allocated, unused)
    aq0 = *reinterpret_cast<const short8*>(qrow + (size_t)(it + 2) * 64 * 64);
    aq1 = *reinterpret_cast<const short8*>(qrow + (size_t)(it + 2) * 64 * 64 + 32);
    __syncthreads();
  }

  // ---- epilogue: + bg (gamma folded into vtilde by prep) ----
#pragma unroll
  for (int tc = 0; tc < 16; ++tc) {
    const float4v bg4 =
        *reinterpret_cast<const float4v*>(&bg[tc * 16 + quad * 4]);
#pragma unroll
    for (int r = 0; r < 4; ++r) {
      const int c = tc * 16 + quad * 4 + r;
      out[((size_t)b * CC + c) * NN + m0 + wid * 16 + l16] =
          acc[tc][r] + bg4[r];
    }
  }
}

// ---------------------------------------------------------------------------
extern "C" void kernel_launch(void* const* d_in, const int* in_sizes, int n_in,
                              void* d_out, int out_size, void* d_ws,
                              size_t ws_size, hipStream_t stream) {
  const float* x  = (const float*)d_in[0];
  const float* wq = (const float*)d_in[1];
  const float* bq = (const float*)d_in[2];
  const float* wk = (const float*)d_in[3];
  const float* bk = (const float*)d_in[4];
  const float* wv = (const float*)d_in[5];
  const float* bv = (const float*)d_in[6];
  const float* wg = (const float*)d_in[7];
  const float* bg = (const float*)d_in[8];
  float* out = (float*)d_out;

  short* qt    = (short*)d_ws;                       // [B][N][64]   4 MB
  short* kt    = qt + (size_t)BB * NN * CQ;          // [B][N][64]   4 MB
  short* vt    = kt + (size_t)BB * NN * CQ;          // [B][C][N]   16 MB
  short* wqbf  = vt + (size_t)BB * CC * NN;          // 32 KB
  short* wkbf  = wqbf + (size_t)CQ * CC;             // 32 KB
  short* wvpbf = wkbf + (size_t)CQ * CC;             // 128 KB
  float* bvp   = (float*)(wvpbf + (size_t)CC * CC);  // 1 KB

  prep_kernel<<<dim3(66), 256, 0, stream>>>(wq, wk, wv, wg, bv,
                                            wqbf, wkbf, wvpbf, bvp);
  qkv_kernel<<<dim3(BB, NN / 32), 256, 0, stream>>>(
      x, wqbf, wkbf, wvpbf, bq, bk, bvp, qt, kt, vt);
  attn_kernel<<<dim3(NN / 64, BB), 256, 0, stream>>>(qt, kt, vt, bg, out);
}